// Round 3
// baseline (144.011 us; speedup 1.0000x reference)
//
#include <hip/hip_runtime.h>

#define EPSV 1e-5f

// ---------------------------------------------------------------------------
// Kernel 1: fold the three branches into one 13x13 depthwise kernel + bias.
//   W_eff[c] = w_large[c]*sl (+ w_small[c]*ss in center 3x3) (+ si at center)
//   bias[c]  = (b_l - m_l*sl) + (b_s - m_s*ss) + (b_i - m_i*si)
// ---------------------------------------------------------------------------
__global__ __launch_bounds__(256) void fuse_weights(
    const float* __restrict__ w_large, const float* __restrict__ w_small,
    const float* __restrict__ g_l, const float* __restrict__ b_l,
    const float* __restrict__ m_l, const float* __restrict__ v_l,
    const float* __restrict__ g_s, const float* __restrict__ b_s,
    const float* __restrict__ m_s, const float* __restrict__ v_s,
    const float* __restrict__ g_i, const float* __restrict__ b_i,
    const float* __restrict__ m_i, const float* __restrict__ v_i,
    float* __restrict__ wf, float* __restrict__ bf) {
    const int c = blockIdx.x;
    const int t = threadIdx.x;
    const float sl = g_l[c] * rsqrtf(v_l[c] + EPSV);
    const float ss = g_s[c] * rsqrtf(v_s[c] + EPSV);
    const float si = g_i[c] * rsqrtf(v_i[c] + EPSV);
    if (t < 169) {
        const int ky = t / 13, kx = t % 13;
        float w = w_large[c * 169 + t] * sl;
        if (ky >= 5 && ky <= 7 && kx >= 5 && kx <= 7)
            w += w_small[c * 9 + (ky - 5) * 3 + (kx - 5)] * ss;
        if (t == 6 * 13 + 6) w += si;
        wf[c * 169 + t] = w;
    }
    if (t == 0)
        bf[c] = (b_l[c] - m_l[c] * sl) + (b_s[c] - m_s[c] * ss) +
                (b_i[c] - m_i[c] * si);
}

// ---------------------------------------------------------------------------
// Kernel 2: depthwise 13x13 + bias over [16,384,64,64] f32 — NO LDS.
// One block (128 threads) per (n,c) image; thread (rg=t>>4, cg=t&15) computes
// an 8x4 output block. x is read directly from global: the 16 KB image lives
// in L1 (one image per block), so window re-reads are L1 hits. Per tap row:
// 5 aligned global_load_dwordx4 covering cols [4cg-8, 4cg+11]; addresses are
// clamped into the image and halo values zeroed via cndmask (exact padding
// semantics, no OOB). Weights are wave-uniform -> s_load -> SGPR FMA operand.
// Runtime tap-row loop (code ~4KB); per-i tap blocks guarded by uniform
// branches so acc indexing stays compile-time static.
// ---------------------------------------------------------------------------
__global__ __launch_bounds__(128, 4) void dwconv13(
    const float* __restrict__ x, const float* __restrict__ wf,
    const float* __restrict__ bf, float* __restrict__ out) {
    const int t = threadIdx.x;          // 0..127
    const int img = blockIdx.x;         // n*384 + c
    const int c = img % 384;
    const size_t base = (size_t)img * 4096;
    const int rg = t >> 4;              // 0..7  -> rows 8*rg .. 8*rg+7
    const int cg = t & 15;              // 0..15 -> cols 4*cg .. 4*cg+3
    const int r0 = rg << 3;
    const int c0 = cg << 2;

    const float* __restrict__ wc = wf + c * 169;
    const float bv = bf[c];

    // per-thread column-vector validity + clamped bases (dr-independent)
    int colbase[5];
    bool colok[5];
#pragma unroll
    for (int q = 0; q < 5; ++q) {
        const int cb = c0 - 8 + 4 * q;          // -8..68, multiple of 4
        colok[q] = (cb >= 0) && (cb <= 60);
        colbase[q] = cb < 0 ? 0 : (cb > 60 ? 60 : cb);
    }

    float acc[8][4];
#pragma unroll
    for (int i = 0; i < 8; ++i)
#pragma unroll
        for (int j = 0; j < 4; ++j) acc[i][j] = bv;

#pragma unroll 1
    for (int dr = 0; dr < 20; ++dr) {
        const int riy = r0 + dr - 6;            // input row, -6..69
        const bool rowok = (riy >= 0) && (riy < 64);
        const int riyc = riy < 0 ? 0 : (riy > 63 ? 63 : riy);
        const float* rowp = x + base + (size_t)riyc * 64;

        float xw[20];                           // input cols c0-8 .. c0+11
#pragma unroll
        for (int q = 0; q < 5; ++q) {
            const float4 v = *(const float4*)(rowp + colbase[q]);
            const bool ok = rowok && colok[q];
            xw[4 * q + 0] = ok ? v.x : 0.0f;
            xw[4 * q + 1] = ok ? v.y : 0.0f;
            xw[4 * q + 2] = ok ? v.z : 0.0f;
            xw[4 * q + 3] = ok ? v.w : 0.0f;
        }

#pragma unroll
        for (int i = 0; i < 8; ++i) {
            const int ky = dr - i;              // tap row for acc row i
            if (ky >= 0 && ky <= 12) {          // uniform runtime branch
                const float* wr = wc + ky * 13;
#pragma unroll
                for (int dc = 0; dc < 13; ++dc) {
                    const float w = wr[dc];
#pragma unroll
                    for (int j = 0; j < 4; ++j)
                        acc[i][j] = fmaf(xw[dc + j + 2], w, acc[i][j]);
                }
            }
        }
    }

    float* ob = out + base + (size_t)r0 * 64 + c0;
#pragma unroll
    for (int i = 0; i < 8; ++i)
        *(float4*)(ob + i * 64) =
            make_float4(acc[i][0], acc[i][1], acc[i][2], acc[i][3]);
}

// ---------------------------------------------------------------------------
extern "C" void kernel_launch(void* const* d_in, const int* in_sizes, int n_in,
                              void* d_out, int out_size, void* d_ws,
                              size_t ws_size, hipStream_t stream) {
    const float* x = (const float*)d_in[0];
    const float* w_large = (const float*)d_in[1];
    const float* w_small = (const float*)d_in[2];
    const float* g_l = (const float*)d_in[3];
    const float* b_l = (const float*)d_in[4];
    const float* m_l = (const float*)d_in[5];
    const float* v_l = (const float*)d_in[6];
    const float* g_s = (const float*)d_in[7];
    const float* b_s = (const float*)d_in[8];
    const float* m_s = (const float*)d_in[9];
    const float* v_s = (const float*)d_in[10];
    const float* g_i = (const float*)d_in[11];
    const float* b_i = (const float*)d_in[12];
    const float* m_i = (const float*)d_in[13];
    const float* v_i = (const float*)d_in[14];
    float* outp = (float*)d_out;

    float* wfp = (float*)d_ws;                  // 384*169 floats
    float* bfp = wfp + 384 * 169;               // 384 floats

    fuse_weights<<<384, 256, 0, stream>>>(w_large, w_small, g_l, b_l, m_l, v_l,
                                          g_s, b_s, m_s, v_s, g_i, b_i, m_i,
                                          v_i, wfp, bfp);
    dwconv13<<<16 * 384, 128, 0, stream>>>(x, wfp, bfp, outp);
}

// Round 4
// 125.625 us; speedup vs baseline: 1.1464x; 1.1464x over previous
//
#include <hip/hip_runtime.h>

#define EPSV 1e-5f

// ---------------------------------------------------------------------------
// Kernel 1: fold the three branches into one 13x13 depthwise kernel + bias.
//   W_eff[c] = w_large[c]*sl (+ w_small[c]*ss in center 3x3) (+ si at center)
//   bias[c]  = (b_l - m_l*sl) + (b_s - m_s*ss) + (b_i - m_i*si)
// ---------------------------------------------------------------------------
__global__ __launch_bounds__(256) void fuse_weights(
    const float* __restrict__ w_large, const float* __restrict__ w_small,
    const float* __restrict__ g_l, const float* __restrict__ b_l,
    const float* __restrict__ m_l, const float* __restrict__ v_l,
    const float* __restrict__ g_s, const float* __restrict__ b_s,
    const float* __restrict__ m_s, const float* __restrict__ v_s,
    const float* __restrict__ g_i, const float* __restrict__ b_i,
    const float* __restrict__ m_i, const float* __restrict__ v_i,
    float* __restrict__ wf, float* __restrict__ bf) {
    const int c = blockIdx.x;
    const int t = threadIdx.x;
    const float sl = g_l[c] * rsqrtf(v_l[c] + EPSV);
    const float ss = g_s[c] * rsqrtf(v_s[c] + EPSV);
    const float si = g_i[c] * rsqrtf(v_i[c] + EPSV);
    if (t < 169) {
        const int ky = t / 13, kx = t % 13;
        float w = w_large[c * 169 + t] * sl;
        if (ky >= 5 && ky <= 7 && kx >= 5 && kx <= 7)
            w += w_small[c * 9 + (ky - 5) * 3 + (kx - 5)] * ss;
        if (t == 6 * 13 + 6) w += si;
        wf[c * 169 + t] = w;
    }
    if (t == 0)
        bf[c] = (b_l[c] - m_l[c] * sl) + (b_s[c] - m_s[c] * ss) +
                (b_i[c] - m_i[c] * si);
}

// ---------------------------------------------------------------------------
// Kernel 2: depthwise 13x13 + bias, [16,384,64,64] f32. NO LDS (0 conflicts);
// x read through L1 (one 16KB image per block). 128 threads/block; thread
// (rg=t>>3, cg=t&7) computes a 4-row x 8-col output block (acc[4][8]).
// Per input row (19 per thread): 6 aligned global_load_dwordx4 covering
// cols [c0-8, c0+15]. Row halo: invalid rows redirect the base pointer to a
// zeroed 80-float row in d_ws (2 cndmask, no per-element masking). Col halo:
// loop-invariant colok[q] selects (only edge threads ever mask). Tap-row
// guards ky=dr-i in [0,12] are scalar-uniform branches. Weights via s_load.
// ---------------------------------------------------------------------------
__global__ __launch_bounds__(128, 4) void dwconv13(
    const float* __restrict__ x, const float* __restrict__ wf,
    const float* __restrict__ bf, const float* __restrict__ zrow,
    float* __restrict__ out) {
    const int t = threadIdx.x;           // 0..127
    const int img = blockIdx.x;          // n*384 + c
    const int c = img % 384;
    const size_t base = (size_t)img * 4096;
    const int rg = t >> 3;               // 0..15 -> rows 4*rg .. 4*rg+3
    const int cg = t & 7;                // 0..7  -> cols 8*cg .. 8*cg+7
    const int r0 = rg << 2;
    const int c0 = cg << 3;

    const float* __restrict__ wc = wf + c * 169;
    const float bv = bf[c];

    // loop-invariant column info for the 6 window chunks [c0-8 .. c0+15]
    int colbase[6];
    bool colok[6];
#pragma unroll
    for (int q = 0; q < 6; ++q) {
        const int cb = c0 - 8 + 4 * q;           // -8 .. 68, multiple of 4
        colok[q] = (cb >= 0) && (cb <= 60);
        colbase[q] = cb < 0 ? 0 : (cb > 60 ? 60 : cb);
    }

    float acc[4][8];
#pragma unroll
    for (int i = 0; i < 4; ++i)
#pragma unroll
        for (int j = 0; j < 8; ++j) acc[i][j] = bv;

#pragma unroll 1
    for (int dr = 0; dr < 19; ++dr) {
        const int riy = r0 + dr - 6;             // input row, -6 .. 72
        const bool rowok = (riy >= 0) && (riy < 64);
        const float* rowp = rowok ? (x + base + (size_t)riy * 64) : zrow;

        float xw[24];                            // input cols c0-8 .. c0+15
#pragma unroll
        for (int q = 0; q < 6; ++q) {
            const float4 v = *(const float4*)(rowp + colbase[q]);
            const bool ok = colok[q];
            xw[4 * q + 0] = ok ? v.x : 0.0f;
            xw[4 * q + 1] = ok ? v.y : 0.0f;
            xw[4 * q + 2] = ok ? v.z : 0.0f;
            xw[4 * q + 3] = ok ? v.w : 0.0f;
        }

#pragma unroll
        for (int i = 0; i < 4; ++i) {
            const int ky = dr - i;               // scalar-uniform
            if (ky >= 0 && ky <= 12) {
                const float* wr = wc + ky * 13;
#pragma unroll
                for (int dc = 0; dc < 13; ++dc) {
                    const float w = wr[dc];
#pragma unroll
                    for (int j = 0; j < 8; ++j)
                        acc[i][j] = fmaf(xw[j + dc + 2], w, acc[i][j]);
                }
            }
        }
    }

    float* ob = out + base + (size_t)r0 * 64 + c0;
#pragma unroll
    for (int i = 0; i < 4; ++i) {
        *(float4*)(ob + i * 64) =
            make_float4(acc[i][0], acc[i][1], acc[i][2], acc[i][3]);
        *(float4*)(ob + i * 64 + 4) =
            make_float4(acc[i][4], acc[i][5], acc[i][6], acc[i][7]);
    }
}

// ---------------------------------------------------------------------------
extern "C" void kernel_launch(void* const* d_in, const int* in_sizes, int n_in,
                              void* d_out, int out_size, void* d_ws,
                              size_t ws_size, hipStream_t stream) {
    const float* x = (const float*)d_in[0];
    const float* w_large = (const float*)d_in[1];
    const float* w_small = (const float*)d_in[2];
    const float* g_l = (const float*)d_in[3];
    const float* b_l = (const float*)d_in[4];
    const float* m_l = (const float*)d_in[5];
    const float* v_l = (const float*)d_in[6];
    const float* g_s = (const float*)d_in[7];
    const float* b_s = (const float*)d_in[8];
    const float* m_s = (const float*)d_in[9];
    const float* v_s = (const float*)d_in[10];
    const float* g_i = (const float*)d_in[11];
    const float* b_i = (const float*)d_in[12];
    const float* m_i = (const float*)d_in[13];
    const float* v_i = (const float*)d_in[14];
    float* outp = (float*)d_out;

    float* wfp = (float*)d_ws;                  // 384*169 floats
    float* bfp = wfp + 384 * 169;               // 384 floats -> ends at 65280
    float* zrow = wfp + 65280;                  // 80 zero floats, 16B-aligned

    hipMemsetAsync(zrow, 0, 80 * sizeof(float), stream);
    fuse_weights<<<384, 256, 0, stream>>>(w_large, w_small, g_l, b_l, m_l, v_l,
                                          g_s, b_s, m_s, v_s, g_i, b_i, m_i,
                                          v_i, wfp, bfp);
    dwconv13<<<16 * 384, 128, 0, stream>>>(x, wfp, bfp, zrow, outp);
}